// Round 16
// baseline (384.631 us; speedup 1.0000x reference)
//
#include <hip/hip_runtime.h>

#define BATCH 4
#define CCH 512
#define NPIX 4096
#define NGRP 32
#define GSZ 16
#define GN_EPS 1e-6f

typedef __attribute__((ext_vector_type(8))) short short8;
typedef __attribute__((ext_vector_type(8))) unsigned short ushort8;
typedef __attribute__((ext_vector_type(4))) unsigned short ushort4v;
typedef __attribute__((ext_vector_type(4))) float f32x4;

__device__ inline unsigned short f2bf(float f) {
  unsigned u = __float_as_uint(f);
  unsigned r = u + 0x7fffu + ((u >> 16) & 1u);
  return (unsigned short)(r >> 16);
}
__device__ inline float bf2f(unsigned short us) {
  return __uint_as_float(((unsigned)us) << 16);
}

// ---------------- GroupNorm stats ----------------
__global__ __launch_bounds__(256) void gn_stats(const float* __restrict__ x,
                                                float* __restrict__ stats) {
  int bg = blockIdx.x;
  const f32x4* base = (const f32x4*)(x + (size_t)bg * (GSZ * NPIX));
  float s = 0.f, ss = 0.f;
  const int n4 = GSZ * NPIX / 4;
  for (int i = threadIdx.x; i < n4; i += 256) {
    f32x4 v = base[i];
    s += v.x + v.y + v.z + v.w;
    ss += v.x * v.x + v.y * v.y + v.z * v.z + v.w * v.w;
  }
  for (int off = 32; off > 0; off >>= 1) {
    s += __shfl_xor(s, off, 64);
    ss += __shfl_xor(ss, off, 64);
  }
  __shared__ float rs[4], rss[4];
  int lane = threadIdx.x & 63, wid = threadIdx.x >> 6;
  if (lane == 0) { rs[wid] = s; rss[wid] = ss; }
  __syncthreads();
  if (threadIdx.x == 0) {
    float S = rs[0] + rs[1] + rs[2] + rs[3];
    float SS = rss[0] + rss[1] + rss[2] + rss[3];
    const float inv = 1.f / (float)(GSZ * NPIX);
    float mean = S * inv;
    float var = SS * inv - mean * mean;
    stats[bg * 2] = mean;
    stats[bg * 2 + 1] = rsqrtf(var + GN_EPS);
  }
}

// ------- GN apply + transpose: x (b,c,n) f32 -> hT (b,n,c) bf16 ----------
__global__ __launch_bounds__(256) void gn_apply_t(const float* __restrict__ x,
                                                  const float* __restrict__ stats,
                                                  const float* __restrict__ gw,
                                                  const float* __restrict__ gb,
                                                  unsigned short* __restrict__ hT) {
  __shared__ float tile[64][65];
  int b = blockIdx.z, c0 = blockIdx.y * 64, n0 = blockIdx.x * 64;
  int t = threadIdx.x;
  int tc4 = t & 15, tr = t >> 4;
  const float* xb = x + ((size_t)b * CCH + c0) * NPIX + n0;
#pragma unroll
  for (int j = 0; j < 4; ++j) {
    int row = tr + j * 16;
    int c = c0 + row;
    float mean = stats[((size_t)b * NGRP + (c >> 4)) * 2];
    float rstd = stats[((size_t)b * NGRP + (c >> 4)) * 2 + 1];
    float ga = gw[c] * rstd;
    float be = gb[c] - mean * ga;
    f32x4 v = *(const f32x4*)(xb + (size_t)row * NPIX + tc4 * 4);
    tile[row][tc4 * 4 + 0] = v.x * ga + be;
    tile[row][tc4 * 4 + 1] = v.y * ga + be;
    tile[row][tc4 * 4 + 2] = v.z * ga + be;
    tile[row][tc4 * 4 + 3] = v.w * ga + be;
  }
  __syncthreads();
  int cc = t & 7, nr = t >> 3;
  unsigned short* outp = hT + ((size_t)b * NPIX + n0) * CCH + c0;
#pragma unroll
  for (int j = 0; j < 2; ++j) {
    int n = nr + j * 32;
    ushort8 pk;
#pragma unroll
    for (int i = 0; i < 8; ++i) pk[i] = f2bf(tile[cc * 8 + i][n]);
    *(ushort8*)(outp + (size_t)n * CCH + cc * 8) = pk;
  }
}

// ------------- fp32 -> bf16 weight conversion (4 mats, one launch) -------
__global__ __launch_bounds__(256) void f32_to_bf16_4(
    const float* __restrict__ s0, const float* __restrict__ s1,
    const float* __restrict__ s2, const float* __restrict__ s3,
    unsigned short* __restrict__ dst, int n4) {
  int m = blockIdx.y;
  const float* src = (m == 0) ? s0 : (m == 1) ? s1 : (m == 2) ? s2 : s3;
  unsigned short* d = dst + (size_t)m * (CCH * CCH);
  int i = blockIdx.x * 256 + threadIdx.x;
  if (i < n4) {
    f32x4 v = ((const f32x4*)src)[i];
    ushort4v o;
    o.x = f2bf(v.x); o.y = f2bf(v.y); o.z = f2bf(v.z); o.w = f2bf(v.w);
    ((ushort4v*)d)[i] = o;
  }
}

// ---------------- B^T GEMM (round-3 proven version) ----------------
template <int BIAS_MODE, int OUT_BF16, int RESID, int SWZ>
__global__ __launch_bounds__(256, 2) void gemm_bt(
    const unsigned short* __restrict__ A, const unsigned short* __restrict__ B,
    void* __restrict__ Cv, const float* __restrict__ bias,
    const float* __restrict__ resid, int M, int N, int K, int lda, int ldb,
    int ldc, long sA, long sB, long sC, long sR, float scale) {
  __shared__ __align__(16) unsigned short lA[128][40];
  __shared__ __align__(16) unsigned short lB[128][40];
  const int t = threadIdx.x;
  const int lane = t & 63, w = t >> 6;
  const int wr = w >> 1, wc = w & 1;
  const int fr = lane & 15, kg = lane >> 4;

  unsigned orig = blockIdx.x + gridDim.x * (blockIdx.y + gridDim.y * blockIdx.z);
  unsigned nwg = gridDim.x * gridDim.y * gridDim.z;
  unsigned tid = (orig & 7) * (nwg >> 3) + (orig >> 3);
  int mt, ntl, bz;
  if (SWZ == 2) {
    unsigned bx = tid % gridDim.x, r = tid / gridDim.x;
    ntl = (int)bx;
    mt = (int)(r % gridDim.y);
    bz = (int)(r / gridDim.y);
  } else {
    unsigned bx = tid % gridDim.x, r = tid / gridDim.x;
    mt = (int)bx;
    ntl = (int)(r % gridDim.y);
    bz = (int)(r / gridDim.y);
  }
  const int m0 = mt * 128, n0 = ntl * 128;

  const unsigned short* Abz = A + (long)bz * sA;
  const unsigned short* Bbz = B + (long)bz * sB;
  const int srow = t >> 1, skc = (t & 1) * 16;
  const unsigned short* gA = Abz + (size_t)(m0 + srow) * lda + skc;
  const unsigned short* gB = Bbz + (size_t)(n0 + srow) * ldb + skc;

  short8 a0X = *(const short8*)(gA);
  short8 a1X = *(const short8*)(gA + 8);
  short8 b0X = *(const short8*)(gB);
  short8 b1X = *(const short8*)(gB + 8);
  short8 a0Y = *(const short8*)(gA + 32);
  short8 a1Y = *(const short8*)(gA + 40);
  short8 b0Y = *(const short8*)(gB + 32);
  short8 b1Y = *(const short8*)(gB + 40);

  f32x4 acc[4][4];
  const f32x4 zero = {0.f, 0.f, 0.f, 0.f};
#pragma unroll
  for (int m = 0; m < 4; ++m)
#pragma unroll
    for (int n = 0; n < 4; ++n) acc[m][n] = zero;

  const int NT = K >> 5;
#define COMPUTE()                                                             \
  do {                                                                        \
    short8 af[4], bfr[4];                                                     \
    _Pragma("unroll") for (int m = 0; m < 4; ++m) af[m] =                     \
        *(const short8*)&lA[wr * 64 + m * 16 + fr][kg * 8];                   \
    _Pragma("unroll") for (int n = 0; n < 4; ++n) bfr[n] =                    \
        *(const short8*)&lB[wc * 64 + n * 16 + fr][kg * 8];                   \
    _Pragma("unroll") for (int m = 0; m < 4; ++m)                             \
        _Pragma("unroll") for (int n = 0; n < 4; ++n) acc[m][n] =             \
            __builtin_amdgcn_mfma_f32_16x16x32_bf16(af[m], bfr[n],            \
                                                    acc[m][n], 0, 0, 0);      \
  } while (0)

  for (int it = 0; it < NT; it += 2) {
    __syncthreads();
    *(short8*)&lA[srow][skc] = a0X;
    *(short8*)&lA[srow][skc + 8] = a1X;
    *(short8*)&lB[srow][skc] = b0X;
    *(short8*)&lB[srow][skc + 8] = b1X;
    if (it + 2 < NT) {
      a0X = *(const short8*)(gA + (it + 2) * 32);
      a1X = *(const short8*)(gA + (it + 2) * 32 + 8);
      b0X = *(const short8*)(gB + (it + 2) * 32);
      b1X = *(const short8*)(gB + (it + 2) * 32 + 8);
    }
    __syncthreads();
    COMPUTE();
    __syncthreads();
    *(short8*)&lA[srow][skc] = a0Y;
    *(short8*)&lA[srow][skc + 8] = a1Y;
    *(short8*)&lB[srow][skc] = b0Y;
    *(short8*)&lB[srow][skc + 8] = b1Y;
    if (it + 3 < NT) {
      a0Y = *(const short8*)(gA + (it + 3) * 32);
      a1Y = *(const short8*)(gA + (it + 3) * 32 + 8);
      b0Y = *(const short8*)(gB + (it + 3) * 32);
      b1Y = *(const short8*)(gB + (it + 3) * 32 + 8);
    }
    __syncthreads();
    COMPUTE();
  }
#undef COMPUTE

  const int rowbase = m0 + wr * 64 + kg * 4;
  const int colbase = n0 + wc * 64 + fr;
#pragma unroll
  for (int m = 0; m < 4; ++m) {
#pragma unroll
    for (int n = 0; n < 4; ++n) {
      int col = colbase + n * 16;
#pragma unroll
      for (int r = 0; r < 4; ++r) {
        int row = rowbase + m * 16 + r;
        float v = acc[m][n][r] * scale;
        if (BIAS_MODE == 1) v += bias[row];
        if (BIAS_MODE == 2) v += bias[col];
        if (RESID) v += resid[(size_t)bz * sR + (size_t)row * ldc + col];
        size_t idx = (size_t)bz * sC + (size_t)row * ldc + col;
        if (OUT_BF16)
          ((unsigned short*)Cv)[idx] = f2bf(v);
        else
          ((float*)Cv)[idx] = v;
      }
    }
  }
}

// ==== fused attention v13: r13 + Q-frags for phases 0-1 held in registers =
// LDS-op census/wave/mt: Q-reads 32, K-reads 32, K-writes 16, V-writes 16,
// V-reads 32, Ps-writes 16, Ps-reads 8 (~152). Q-reads re-fetch IDENTICAL
// data all 32 mt iterations. Cache phases 0-1's 16 frags (64 VGPRs, est
// total ~185 < 256 budget; occupancy is LDS-bound so VGPR increase is free).
// Deletes 16/152 ops (-10.5%).
__global__ __launch_bounds__(512, 2) void attn_fused(
    const unsigned short* __restrict__ qg, const unsigned short* __restrict__ kgl,
    const unsigned short* __restrict__ vg, unsigned short* __restrict__ og,
    float scale) {
  __shared__ __align__(16) unsigned short Qs[64 * 512];     // 64 KB
  __shared__ __align__(16) unsigned short Ck[2][16384];     // 2 x 32 KB
  __shared__ __align__(16) unsigned short Ps[64 * 128];     // 16 KB
  __shared__ float lred[2][32][4];
  __shared__ float linv[64];

  const int t = threadIdx.x;
  const int lane = t & 63;
  const int wid = t >> 6;
  const int wq = wid >> 2, wc = wid & 3;
  const int fr = lane & 15, kgp = lane >> 4;

  unsigned logical = ((unsigned)blockIdx.x & 7) * 32 + ((unsigned)blockIdx.x >> 3);
  const int bz = (int)(logical >> 6), qt = (int)(logical & 63);
  const size_t BS = (size_t)NPIX * CCH;
  const unsigned short* qb = qg + (size_t)bz * BS + (size_t)qt * 64 * CCH;
  const unsigned short* kb = kgl + (size_t)bz * BS;
  const unsigned short* vb = vg + (size_t)bz * BS;

  // Q -> LDS (xor-swizzled)
  {
    const int row = t >> 3, c0 = (t & 7) * 64;
    const unsigned short* src = qb + (size_t)row * CCH + c0;
    const int sw = (row & 7) << 3;
#pragma unroll
    for (int i = 0; i < 8; ++i)
      *(short8*)&Qs[row * 512 + ((c0 + i * 8) ^ sw)] = *(const short8*)(src + i * 8);
  }

  // staging geometry
  const int krow = t >> 2, kseg = t & 3;      // K: row 0..127, 32-col segment
  const int kswz = (krow & 7) << 3;
  const unsigned short* gK = kb + (size_t)krow * CCH + kseg * 32;
  const unsigned short* gV = vb + (size_t)t * NPIX;

  short8 R0, R1, R2, R3;
#define LOADK(mt_, cc_)                                                       \
  do { const unsigned short* g = gK + (size_t)(mt_) * (128 * CCH) + (cc_) * 128; \
    R0 = *(const short8*)(g); R1 = *(const short8*)(g + 8);                   \
    R2 = *(const short8*)(g + 16); R3 = *(const short8*)(g + 24); } while (0)
#define LOADV(mt_, vc_)                                                       \
  do { const unsigned short* g = gV + (mt_) * 128 + (vc_) * 32;               \
    R0 = *(const short8*)(g); R1 = *(const short8*)(g + 8);                   \
    R2 = *(const short8*)(g + 16); R3 = *(const short8*)(g + 24); } while (0)
#define WRITEK(buf_)                                                          \
  do { unsigned short* d = &Ck[buf_][krow * 128];                             \
    *(short8*)(d + ((kseg * 32 + 0) ^ kswz)) = R0;                            \
    *(short8*)(d + ((kseg * 32 + 8) ^ kswz)) = R1;                            \
    *(short8*)(d + ((kseg * 32 + 16) ^ kswz)) = R2;                           \
    *(short8*)(d + ((kseg * 32 + 24) ^ kswz)) = R3; } while (0)
#define WRITEV(buf_)                                                          \
  do { unsigned short* d = &Ck[buf_][t * 8];                                  \
    *(short8*)(d + 0 * 4096) = R0; *(short8*)(d + 1 * 4096) = R1;             \
    *(short8*)(d + 2 * 4096) = R2; *(short8*)(d + 3 * 4096) = R3; } while (0)

// counted-wait phase barrier (T4): lgkmcnt(0) only; vmcnt stays outstanding.
#define PHASE_BAR()                                                           \
  do {                                                                        \
    __builtin_amdgcn_sched_barrier(0);                                        \
    asm volatile("s_waitcnt lgkmcnt(0)" ::: "memory");                        \
    __builtin_amdgcn_s_barrier();                                             \
    __builtin_amdgcn_sched_barrier(0);                                        \
  } while (0)

  f32x4 oa[2][8];
  const f32x4 zero = {0.f, 0.f, 0.f, 0.f};
#pragma unroll
  for (int i = 0; i < 2; ++i)
#pragma unroll
    for (int j = 0; j < 8; ++j) oa[i][j] = zero;
  f32x4 racc0 = zero, racc1 = zero;

  short8 ones;
#pragma unroll
  for (int i = 0; i < 8; ++i) ones[i] = (short)0x3F80;  // bf16 1.0

  // ---- hold Q-frags for K-phases 0-1 in registers (mt-invariant) ----
  const int q0 = wq * 32 + fr, q1 = wq * 32 + 16 + fr;
  const int q0x = (q0 & 7) << 3, q1x = (q1 & 7) << 3;
  short8 qfA[2][4], qfB[2][4];
  __syncthreads();  // Q staging complete
#pragma unroll
  for (int qp = 0; qp < 2; ++qp)
#pragma unroll
    for (int kk = 0; kk < 4; ++kk) {
      const int col = qp * 128 + kk * 32 + kgp * 8;
      qfA[qp][kk] = *(const short8*)&Qs[q0 * 512 + (col ^ q0x)];
      qfB[qp][kk] = *(const short8*)&Qs[q1 * 512 + (col ^ q1x)];
    }

  LOADK(0, 0);
  for (int mt = 0; mt < 32; ++mt) {
    f32x4 s00 = zero, s01 = zero, s10 = zero, s11 = zero;
#pragma unroll
    for (int ph = 0; ph < 8; ++ph) {
      const int buf = ph & 1;
      if (ph < 4) WRITEK(buf); else WRITEV(buf);
      // issue next phase's loads (stay in flight across the barrier)
      if (ph < 3) { LOADK(mt, ph + 1); }
      else if (ph == 3) { LOADV(mt, 0); }
      else if (ph < 7) { LOADV(mt, ph - 3); }
      else { if (mt + 1 < 32) LOADK(mt + 1, 0); }
      PHASE_BAR();
      if (ph < 4) {
        // S-chunk: c in [ph*128, ph*128+128)
        __builtin_amdgcn_s_setprio(1);
#pragma unroll
        for (int kk = 0; kk < 4; ++kk) {
          short8 a0, a1;
          if (ph < 2) {
            a0 = qfA[ph][kk];
            a1 = qfB[ph][kk];
          } else {
            const int col = ph * 128 + kk * 32 + kgp * 8;
            a0 = *(const short8*)&Qs[q0 * 512 + (col ^ q0x)];
            a1 = *(const short8*)&Qs[q1 * 512 + (col ^ q1x)];
          }
          const int m0r = wc * 32 + fr, m1r = wc * 32 + 16 + fr;
          short8 b0 = *(const short8*)&Ck[buf][m0r * 128 +
                      ((kk * 32 + kgp * 8) ^ ((m0r & 7) << 3))];
          short8 b1 = *(const short8*)&Ck[buf][m1r * 128 +
                      ((kk * 32 + kgp * 8) ^ ((m1r & 7) << 3))];
          s00 = __builtin_amdgcn_mfma_f32_16x16x32_bf16(a0, b0, s00, 0, 0, 0);
          s01 = __builtin_amdgcn_mfma_f32_16x16x32_bf16(a0, b1, s01, 0, 0, 0);
          s10 = __builtin_amdgcn_mfma_f32_16x16x32_bf16(a1, b0, s10, 0, 0, 0);
          s11 = __builtin_amdgcn_mfma_f32_16x16x32_bf16(a1, b1, s11, 0, 0, 0);
        }
        __builtin_amdgcn_s_setprio(0);
        if (ph == 3) {
          // P = exp(S*scale); P -> Ps (C/D layout [m89]). Row-sums are
          // computed by MFMA in the PV phases (pa . ones).
          f32x4 p00, p01, p10, p11;
#pragma unroll
          for (int r = 0; r < 4; ++r) {
            p00[r] = __expf(s00[r] * scale);
            p01[r] = __expf(s01[r] * scale);
            p10[r] = __expf(s10[r] * scale);
            p11[r] = __expf(s11[r] * scale);
          }
#pragma unroll
          for (int r = 0; r < 4; ++r) {
            const int qa = wq * 32 + kgp * 4 + r;
            const int qbr = wq * 32 + 16 + kgp * 4 + r;
            const int swa = (qa & 7) << 3, swb = (qbr & 7) << 3;
            Ps[qa * 128 + ((wc * 32 + fr) ^ swa)] = f2bf(p00[r]);
            Ps[qa * 128 + ((wc * 32 + 16 + fr) ^ swa)] = f2bf(p01[r]);
            Ps[qbr * 128 + ((wc * 32 + fr) ^ swb)] = f2bf(p10[r]);
            Ps[qbr * 128 + ((wc * 32 + 16 + fr) ^ swb)] = f2bf(p11[r]);
          }
          s00 = zero; s01 = zero; s10 = zero; s11 = zero;
        }
      } else {
        const int vc = ph - 4;  // m sub-block within the 128-m tile
        short8 pa0 = *(const short8*)&Ps[q0 * 128 +
                     ((vc * 32 + kgp * 8) ^ q0x)];
        short8 pa1 = *(const short8*)&Ps[q1 * 128 +
                     ((vc * 32 + kgp * 8) ^ q1x)];
        __builtin_amdgcn_s_setprio(1);
        // row-sum via MFMA: D[q][*] = sum_k pa[q][k] (B = ones)
        racc0 = __builtin_amdgcn_mfma_f32_16x16x32_bf16(pa0, ones, racc0, 0, 0, 0);
        racc1 = __builtin_amdgcn_mfma_f32_16x16x32_bf16(pa1, ones, racc1, 0, 0, 0);
#pragma unroll
        for (int fb = 0; fb < 8; ++fb) {
          const int c = wc * 128 + fb * 16 + fr;
          short8 bv = *(const short8*)&Ck[buf][kgp * 4096 + c * 8];
          oa[0][fb] = __builtin_amdgcn_mfma_f32_16x16x32_bf16(pa0, bv, oa[0][fb], 0, 0, 0);
          oa[1][fb] = __builtin_amdgcn_mfma_f32_16x16x32_bf16(pa1, bv, oa[1][fb], 0, 0, 0);
        }
        __builtin_amdgcn_s_setprio(0);
      }
    }
  }
#undef LOADK
#undef LOADV
#undef WRITEK
#undef WRITEV
#undef PHASE_BAR

  // l reduction across the 4 wc-waves (each wave's racc covers ALL m -> 4x)
  __syncthreads();
  if (fr == 0) {
#pragma unroll
    for (int r = 0; r < 4; ++r) {
      lred[wq][kgp * 4 + r][wc] = racc0[r];
      lred[wq][16 + kgp * 4 + r][wc] = racc1[r];
    }
  }
  __syncthreads();
  if (t < 64) {
    float s = lred[t >> 5][t & 31][0] + lred[t >> 5][t & 31][1] +
              lred[t >> 5][t & 31][2] + lred[t >> 5][t & 31][3];
    linv[t] = 4.f / s;  // each wc wave summed all m -> sum is 4x true l
  }
  __syncthreads();
  // scale + transpose-stage O into Qs (Q dead), then coalesced store
#pragma unroll
  for (int i = 0; i < 2; ++i) {
    f32x4 li = *(const f32x4*)&linv[wq * 32 + i * 16 + kgp * 4];
#pragma unroll
    for (int fb = 0; fb < 8; ++fb) {
#pragma unroll
      for (int r = 0; r < 4; ++r) {
        const int q = wq * 32 + i * 16 + kgp * 4 + r;
        const int col = wc * 128 + fb * 16 + fr;
        Qs[q * 512 + (col ^ ((q & 7) << 3))] = f2bf(oa[i][fb][r] * li[r]);
      }
    }
  }
  __syncthreads();
  {
    const int row = t >> 3, c0 = (t & 7) * 64;
    const int sw = (row & 7) << 3;
    unsigned short* dst = og + (size_t)bz * BS + ((size_t)qt * 64 + row) * CCH + c0;
#pragma unroll
    for (int i = 0; i < 8; ++i)
      *(short8*)(dst + i * 8) = *(const short8*)&Qs[row * 512 + ((c0 + i * 8) ^ sw)];
  }
}

extern "C" void kernel_launch(void* const* d_in, const int* in_sizes, int n_in,
                              void* d_out, int out_size, void* d_ws, size_t ws_size,
                              hipStream_t stream) {
  const float* x = (const float*)d_in[0];
  const float* gnw = (const float*)d_in[1];
  const float* gnb = (const float*)d_in[2];
  const float* wq = (const float*)d_in[3];
  const float* bq = (const float*)d_in[4];
  const float* wk = (const float*)d_in[5];
  const float* bk = (const float*)d_in[6];
  const float* wv = (const float*)d_in[7];
  const float* bv = (const float*)d_in[8];
  const float* wp = (const float*)d_in[9];
  const float* bp = (const float*)d_in[10];
  float* out = (float*)d_out;

  const size_t BS = (size_t)NPIX * CCH;

  char* ws = (char*)d_ws;
  float* stats = (float*)ws;
  unsigned short* hT = (unsigned short*)(ws + 1024);
  unsigned short* Abuf = hT;  // aliases hT (dead after v-GEMM)
  unsigned short* qb = hT + BATCH * BS;
  unsigned short* kTb = qb + BATCH * BS;
  unsigned short* vb = kTb + BATCH * BS;
  unsigned short* wqb = vb + BATCH * BS;  // wqb..wpb contiguous (4x CCH*CCH)
  unsigned short* wkb = wqb + CCH * CCH;
  unsigned short* wvb = wkb + CCH * CCH;
  unsigned short* wpb = wvb + CCH * CCH;
  size_t need = (size_t)((char*)(wpb + CCH * CCH) - ws);
  if (ws_size < need) return;

  f32_to_bf16_4<<<dim3(256, 4), 256, 0, stream>>>(wq, wk, wv, wp, wqb,
                                                  CCH * CCH / 4);

  gn_stats<<<BATCH * NGRP, 256, 0, stream>>>(x, stats);
  gn_apply_t<<<dim3(NPIX / 64, CCH / 64, BATCH), 256, 0, stream>>>(x, stats, gnw,
                                                                   gnb, hT);

  // q[n,o] = sum_c hT[n,c] wq[o,c] + bq[o]
  gemm_bt<2, 1, 0, 2><<<dim3(4, 32, BATCH), 256, 0, stream>>>(
      hT, wqb, qb, bq, nullptr, NPIX, CCH, CCH, CCH, CCH, CCH, (long)BS, 0,
      (long)BS, 0, 1.f);
  // kT[m,o] = sum_c hT[m,c] wk[o,c] + bk[o]
  gemm_bt<2, 1, 0, 2><<<dim3(4, 32, BATCH), 256, 0, stream>>>(
      hT, wkb, kTb, bk, nullptr, NPIX, CCH, CCH, CCH, CCH, CCH, (long)BS, 0,
      (long)BS, 0, 1.f);
  // v[c,m] = sum_c' wv[c,c'] hT[m,c'] + bv[c]
  gemm_bt<1, 1, 0, 0><<<dim3(4, 32, BATCH), 256, 0, stream>>>(
      wvb, hT, vb, bv, nullptr, CCH, NPIX, CCH, CCH, CCH, NPIX, 0, (long)BS,
      (long)BS, 0, 1.f);

  const float sscale = 0.044194173824159216f;  // 512^-0.5
  attn_fused<<<BATCH * 64, 512, 0, stream>>>(qb, kTb, vb, Abuf, sscale);

  // out[o,n] = sum_c wp[o,c] AoutT[n,c] + bp[o] + x[b,o,n]
  gemm_bt<1, 0, 1, 0><<<dim3(4, 32, BATCH), 256, 0, stream>>>(
      wpb, Abuf, out, bp, x, CCH, NPIX, CCH, CCH, CCH, NPIX, 0, (long)BS,
      (long)BS, (long)BS, 1.f);
}

// Round 17
// 316.095 us; speedup vs baseline: 1.2168x; 1.2168x over previous
//
#include <hip/hip_runtime.h>

#define BATCH 4
#define CCH 512
#define NPIX 4096
#define NGRP 32
#define GSZ 16
#define GN_EPS 1e-6f

typedef __attribute__((ext_vector_type(8))) short short8;
typedef __attribute__((ext_vector_type(8))) unsigned short ushort8;
typedef __attribute__((ext_vector_type(4))) unsigned short ushort4v;
typedef __attribute__((ext_vector_type(4))) float f32x4;

__device__ inline unsigned short f2bf(float f) {
  unsigned u = __float_as_uint(f);
  unsigned r = u + 0x7fffu + ((u >> 16) & 1u);
  return (unsigned short)(r >> 16);
}
__device__ inline float bf2f(unsigned short us) {
  return __uint_as_float(((unsigned)us) << 16);
}

// ---------------- GroupNorm stats ----------------
__global__ __launch_bounds__(256) void gn_stats(const float* __restrict__ x,
                                                float* __restrict__ stats) {
  int bg = blockIdx.x;
  const f32x4* base = (const f32x4*)(x + (size_t)bg * (GSZ * NPIX));
  float s = 0.f, ss = 0.f;
  const int n4 = GSZ * NPIX / 4;
  for (int i = threadIdx.x; i < n4; i += 256) {
    f32x4 v = base[i];
    s += v.x + v.y + v.z + v.w;
    ss += v.x * v.x + v.y * v.y + v.z * v.z + v.w * v.w;
  }
  for (int off = 32; off > 0; off >>= 1) {
    s += __shfl_xor(s, off, 64);
    ss += __shfl_xor(ss, off, 64);
  }
  __shared__ float rs[4], rss[4];
  int lane = threadIdx.x & 63, wid = threadIdx.x >> 6;
  if (lane == 0) { rs[wid] = s; rss[wid] = ss; }
  __syncthreads();
  if (threadIdx.x == 0) {
    float S = rs[0] + rs[1] + rs[2] + rs[3];
    float SS = rss[0] + rss[1] + rss[2] + rss[3];
    const float inv = 1.f / (float)(GSZ * NPIX);
    float mean = S * inv;
    float var = SS * inv - mean * mean;
    stats[bg * 2] = mean;
    stats[bg * 2 + 1] = rsqrtf(var + GN_EPS);
  }
}

// ------- GN apply + transpose: x (b,c,n) f32 -> hT (b,n,c) bf16 ----------
__global__ __launch_bounds__(256) void gn_apply_t(const float* __restrict__ x,
                                                  const float* __restrict__ stats,
                                                  const float* __restrict__ gw,
                                                  const float* __restrict__ gb,
                                                  unsigned short* __restrict__ hT) {
  __shared__ float tile[64][65];
  int b = blockIdx.z, c0 = blockIdx.y * 64, n0 = blockIdx.x * 64;
  int t = threadIdx.x;
  int tc4 = t & 15, tr = t >> 4;
  const float* xb = x + ((size_t)b * CCH + c0) * NPIX + n0;
#pragma unroll
  for (int j = 0; j < 4; ++j) {
    int row = tr + j * 16;
    int c = c0 + row;
    float mean = stats[((size_t)b * NGRP + (c >> 4)) * 2];
    float rstd = stats[((size_t)b * NGRP + (c >> 4)) * 2 + 1];
    float ga = gw[c] * rstd;
    float be = gb[c] - mean * ga;
    f32x4 v = *(const f32x4*)(xb + (size_t)row * NPIX + tc4 * 4);
    tile[row][tc4 * 4 + 0] = v.x * ga + be;
    tile[row][tc4 * 4 + 1] = v.y * ga + be;
    tile[row][tc4 * 4 + 2] = v.z * ga + be;
    tile[row][tc4 * 4 + 3] = v.w * ga + be;
  }
  __syncthreads();
  int cc = t & 7, nr = t >> 3;
  unsigned short* outp = hT + ((size_t)b * NPIX + n0) * CCH + c0;
#pragma unroll
  for (int j = 0; j < 2; ++j) {
    int n = nr + j * 32;
    ushort8 pk;
#pragma unroll
    for (int i = 0; i < 8; ++i) pk[i] = f2bf(tile[cc * 8 + i][n]);
    *(ushort8*)(outp + (size_t)n * CCH + cc * 8) = pk;
  }
}

// ------------- fp32 -> bf16 weight conversion (4 mats, one launch) -------
__global__ __launch_bounds__(256) void f32_to_bf16_4(
    const float* __restrict__ s0, const float* __restrict__ s1,
    const float* __restrict__ s2, const float* __restrict__ s3,
    unsigned short* __restrict__ dst, int n4) {
  int m = blockIdx.y;
  const float* src = (m == 0) ? s0 : (m == 1) ? s1 : (m == 2) ? s2 : s3;
  unsigned short* d = dst + (size_t)m * (CCH * CCH);
  int i = blockIdx.x * 256 + threadIdx.x;
  if (i < n4) {
    f32x4 v = ((const f32x4*)src)[i];
    ushort4v o;
    o.x = f2bf(v.x); o.y = f2bf(v.y); o.z = f2bf(v.z); o.w = f2bf(v.w);
    ((ushort4v*)d)[i] = o;
  }
}

// ---------------- B^T GEMM (round-3 proven version) ----------------
template <int BIAS_MODE, int OUT_BF16, int RESID, int SWZ>
__global__ __launch_bounds__(256, 2) void gemm_bt(
    const unsigned short* __restrict__ A, const unsigned short* __restrict__ B,
    void* __restrict__ Cv, const float* __restrict__ bias,
    const float* __restrict__ resid, int M, int N, int K, int lda, int ldb,
    int ldc, long sA, long sB, long sC, long sR, float scale) {
  __shared__ __align__(16) unsigned short lA[128][40];
  __shared__ __align__(16) unsigned short lB[128][40];
  const int t = threadIdx.x;
  const int lane = t & 63, w = t >> 6;
  const int wr = w >> 1, wc = w & 1;
  const int fr = lane & 15, kg = lane >> 4;

  unsigned orig = blockIdx.x + gridDim.x * (blockIdx.y + gridDim.y * blockIdx.z);
  unsigned nwg = gridDim.x * gridDim.y * gridDim.z;
  unsigned tid = (orig & 7) * (nwg >> 3) + (orig >> 3);
  int mt, ntl, bz;
  if (SWZ == 2) {
    unsigned bx = tid % gridDim.x, r = tid / gridDim.x;
    ntl = (int)bx;
    mt = (int)(r % gridDim.y);
    bz = (int)(r / gridDim.y);
  } else {
    unsigned bx = tid % gridDim.x, r = tid / gridDim.x;
    mt = (int)bx;
    ntl = (int)(r % gridDim.y);
    bz = (int)(r / gridDim.y);
  }
  const int m0 = mt * 128, n0 = ntl * 128;

  const unsigned short* Abz = A + (long)bz * sA;
  const unsigned short* Bbz = B + (long)bz * sB;
  const int srow = t >> 1, skc = (t & 1) * 16;
  const unsigned short* gA = Abz + (size_t)(m0 + srow) * lda + skc;
  const unsigned short* gB = Bbz + (size_t)(n0 + srow) * ldb + skc;

  short8 a0X = *(const short8*)(gA);
  short8 a1X = *(const short8*)(gA + 8);
  short8 b0X = *(const short8*)(gB);
  short8 b1X = *(const short8*)(gB + 8);
  short8 a0Y = *(const short8*)(gA + 32);
  short8 a1Y = *(const short8*)(gA + 40);
  short8 b0Y = *(const short8*)(gB + 32);
  short8 b1Y = *(const short8*)(gB + 40);

  f32x4 acc[4][4];
  const f32x4 zero = {0.f, 0.f, 0.f, 0.f};
#pragma unroll
  for (int m = 0; m < 4; ++m)
#pragma unroll
    for (int n = 0; n < 4; ++n) acc[m][n] = zero;

  const int NT = K >> 5;
#define COMPUTE()                                                             \
  do {                                                                        \
    short8 af[4], bfr[4];                                                     \
    _Pragma("unroll") for (int m = 0; m < 4; ++m) af[m] =                     \
        *(const short8*)&lA[wr * 64 + m * 16 + fr][kg * 8];                   \
    _Pragma("unroll") for (int n = 0; n < 4; ++n) bfr[n] =                    \
        *(const short8*)&lB[wc * 64 + n * 16 + fr][kg * 8];                   \
    _Pragma("unroll") for (int m = 0; m < 4; ++m)                             \
        _Pragma("unroll") for (int n = 0; n < 4; ++n) acc[m][n] =             \
            __builtin_amdgcn_mfma_f32_16x16x32_bf16(af[m], bfr[n],            \
                                                    acc[m][n], 0, 0, 0);      \
  } while (0)

  for (int it = 0; it < NT; it += 2) {
    __syncthreads();
    *(short8*)&lA[srow][skc] = a0X;
    *(short8*)&lA[srow][skc + 8] = a1X;
    *(short8*)&lB[srow][skc] = b0X;
    *(short8*)&lB[srow][skc + 8] = b1X;
    if (it + 2 < NT) {
      a0X = *(const short8*)(gA + (it + 2) * 32);
      a1X = *(const short8*)(gA + (it + 2) * 32 + 8);
      b0X = *(const short8*)(gB + (it + 2) * 32);
      b1X = *(const short8*)(gB + (it + 2) * 32 + 8);
    }
    __syncthreads();
    COMPUTE();
    __syncthreads();
    *(short8*)&lA[srow][skc] = a0Y;
    *(short8*)&lA[srow][skc + 8] = a1Y;
    *(short8*)&lB[srow][skc] = b0Y;
    *(short8*)&lB[srow][skc + 8] = b1Y;
    if (it + 3 < NT) {
      a0Y = *(const short8*)(gA + (it + 3) * 32);
      a1Y = *(const short8*)(gA + (it + 3) * 32 + 8);
      b0Y = *(const short8*)(gB + (it + 3) * 32);
      b1Y = *(const short8*)(gB + (it + 3) * 32 + 8);
    }
    __syncthreads();
    COMPUTE();
  }
#undef COMPUTE

  const int rowbase = m0 + wr * 64 + kg * 4;
  const int colbase = n0 + wc * 64 + fr;
#pragma unroll
  for (int m = 0; m < 4; ++m) {
#pragma unroll
    for (int n = 0; n < 4; ++n) {
      int col = colbase + n * 16;
#pragma unroll
      for (int r = 0; r < 4; ++r) {
        int row = rowbase + m * 16 + r;
        float v = acc[m][n][r] * scale;
        if (BIAS_MODE == 1) v += bias[row];
        if (BIAS_MODE == 2) v += bias[col];
        if (RESID) v += resid[(size_t)bz * sR + (size_t)row * ldc + col];
        size_t idx = (size_t)bz * sC + (size_t)row * ldc + col;
        if (OUT_BF16)
          ((unsigned short*)Cv)[idx] = f2bf(v);
        else
          ((float*)Cv)[idx] = v;
      }
    }
  }
}

// ====== fused attention (final best: MFMA row-sum, reg-staged K/V) ========
__global__ __launch_bounds__(512, 2) void attn_fused(
    const unsigned short* __restrict__ qg, const unsigned short* __restrict__ kgl,
    const unsigned short* __restrict__ vg, unsigned short* __restrict__ og,
    float scale) {
  __shared__ __align__(16) unsigned short Qs[64 * 512];     // 64 KB
  __shared__ __align__(16) unsigned short Ck[2][16384];     // 2 x 32 KB
  __shared__ __align__(16) unsigned short Ps[64 * 128];     // 16 KB
  __shared__ float lred[2][32][4];
  __shared__ float linv[64];

  const int t = threadIdx.x;
  const int lane = t & 63;
  const int wid = t >> 6;
  const int wq = wid >> 2, wc = wid & 3;
  const int fr = lane & 15, kgp = lane >> 4;

  unsigned logical = ((unsigned)blockIdx.x & 7) * 32 + ((unsigned)blockIdx.x >> 3);
  const int bz = (int)(logical >> 6), qt = (int)(logical & 63);
  const size_t BS = (size_t)NPIX * CCH;
  const unsigned short* qb = qg + (size_t)bz * BS + (size_t)qt * 64 * CCH;
  const unsigned short* kb = kgl + (size_t)bz * BS;
  const unsigned short* vb = vg + (size_t)bz * BS;

  // Q -> LDS (xor-swizzled; synced by first phase barrier)
  {
    const int row = t >> 3, c0 = (t & 7) * 64;
    const unsigned short* src = qb + (size_t)row * CCH + c0;
    const int sw = (row & 7) << 3;
#pragma unroll
    for (int i = 0; i < 8; ++i)
      *(short8*)&Qs[row * 512 + ((c0 + i * 8) ^ sw)] = *(const short8*)(src + i * 8);
  }

  // staging geometry
  const int krow = t >> 2, kseg = t & 3;      // K: row 0..127, 32-col segment
  const int kswz = (krow & 7) << 3;
  const unsigned short* gK = kb + (size_t)krow * CCH + kseg * 32;
  const unsigned short* gV = vb + (size_t)t * NPIX;

  short8 R0, R1, R2, R3;
#define LOADK(mt_, cc_)                                                       \
  do { const unsigned short* g = gK + (size_t)(mt_) * (128 * CCH) + (cc_) * 128; \
    R0 = *(const short8*)(g); R1 = *(const short8*)(g + 8);                   \
    R2 = *(const short8*)(g + 16); R3 = *(const short8*)(g + 24); } while (0)
#define LOADV(mt_, vc_)                                                       \
  do { const unsigned short* g = gV + (mt_) * 128 + (vc_) * 32;               \
    R0 = *(const short8*)(g); R1 = *(const short8*)(g + 8);                   \
    R2 = *(const short8*)(g + 16); R3 = *(const short8*)(g + 24); } while (0)
#define WRITEK(buf_)                                                          \
  do { unsigned short* d = &Ck[buf_][krow * 128];                             \
    *(short8*)(d + ((kseg * 32 + 0) ^ kswz)) = R0;                            \
    *(short8*)(d + ((kseg * 32 + 8) ^ kswz)) = R1;                            \
    *(short8*)(d + ((kseg * 32 + 16) ^ kswz)) = R2;                           \
    *(short8*)(d + ((kseg * 32 + 24) ^ kswz)) = R3; } while (0)
#define WRITEV(buf_)                                                          \
  do { unsigned short* d = &Ck[buf_][t * 8];                                  \
    *(short8*)(d + 0 * 4096) = R0; *(short8*)(d + 1 * 4096) = R1;             \
    *(short8*)(d + 2 * 4096) = R2; *(short8*)(d + 3 * 4096) = R3; } while (0)

// counted-wait phase barrier (T4): lgkmcnt(0) only; vmcnt stays outstanding.
#define PHASE_BAR()                                                           \
  do {                                                                        \
    __builtin_amdgcn_sched_barrier(0);                                        \
    asm volatile("s_waitcnt lgkmcnt(0)" ::: "memory");                        \
    __builtin_amdgcn_s_barrier();                                             \
    __builtin_amdgcn_sched_barrier(0);                                        \
  } while (0)

  f32x4 oa[2][8];
  const f32x4 zero = {0.f, 0.f, 0.f, 0.f};
#pragma unroll
  for (int i = 0; i < 2; ++i)
#pragma unroll
    for (int j = 0; j < 8; ++j) oa[i][j] = zero;
  f32x4 racc0 = zero, racc1 = zero;

  short8 ones;
#pragma unroll
  for (int i = 0; i < 8; ++i) ones[i] = (short)0x3F80;  // bf16 1.0

  LOADK(0, 0);
  for (int mt = 0; mt < 32; ++mt) {
    f32x4 s00 = zero, s01 = zero, s10 = zero, s11 = zero;
#pragma unroll
    for (int ph = 0; ph < 8; ++ph) {
      const int buf = ph & 1;
      if (ph < 4) WRITEK(buf); else WRITEV(buf);
      // issue next phase's loads (stay in flight across the barrier)
      if (ph < 3) { LOADK(mt, ph + 1); }
      else if (ph == 3) { LOADV(mt, 0); }
      else if (ph < 7) { LOADV(mt, ph - 3); }
      else { if (mt + 1 < 32) LOADK(mt + 1, 0); }
      PHASE_BAR();
      if (ph < 4) {
        // S-chunk: c in [ph*128, ph*128+128)
        __builtin_amdgcn_s_setprio(1);
#pragma unroll
        for (int kk = 0; kk < 4; ++kk) {
          const int q0 = wq * 32 + fr, q1 = wq * 32 + 16 + fr;
          const int col = ph * 128 + kk * 32 + kgp * 8;
          short8 a0 = *(const short8*)&Qs[q0 * 512 + ((col) ^ ((q0 & 7) << 3))];
          short8 a1 = *(const short8*)&Qs[q1 * 512 + ((col) ^ ((q1 & 7) << 3))];
          const int m0r = wc * 32 + fr, m1r = wc * 32 + 16 + fr;
          short8 b0 = *(const short8*)&Ck[buf][m0r * 128 +
                      ((kk * 32 + kgp * 8) ^ ((m0r & 7) << 3))];
          short8 b1 = *(const short8*)&Ck[buf][m1r * 128 +
                      ((kk * 32 + kgp * 8) ^ ((m1r & 7) << 3))];
          s00 = __builtin_amdgcn_mfma_f32_16x16x32_bf16(a0, b0, s00, 0, 0, 0);
          s01 = __builtin_amdgcn_mfma_f32_16x16x32_bf16(a0, b1, s01, 0, 0, 0);
          s10 = __builtin_amdgcn_mfma_f32_16x16x32_bf16(a1, b0, s10, 0, 0, 0);
          s11 = __builtin_amdgcn_mfma_f32_16x16x32_bf16(a1, b1, s11, 0, 0, 0);
        }
        __builtin_amdgcn_s_setprio(0);
        if (ph == 3) {
          // P = exp(S*scale); P -> Ps (C/D layout [m89]). Row-sums are
          // computed by MFMA in the PV phases (pa . ones).
          f32x4 p00, p01, p10, p11;
#pragma unroll
          for (int r = 0; r < 4; ++r) {
            p00[r] = __expf(s00[r] * scale);
            p01[r] = __expf(s01[r] * scale);
            p10[r] = __expf(s10[r] * scale);
            p11[r] = __expf(s11[r] * scale);
          }
#pragma unroll
          for (int r = 0; r < 4; ++r) {
            const int qa = wq * 32 + kgp * 4 + r;
            const int qbr = wq * 32 + 16 + kgp * 4 + r;
            const int swa = (qa & 7) << 3, swb = (qbr & 7) << 3;
            Ps[qa * 128 + ((wc * 32 + fr) ^ swa)] = f2bf(p00[r]);
            Ps[qa * 128 + ((wc * 32 + 16 + fr) ^ swa)] = f2bf(p01[r]);
            Ps[qbr * 128 + ((wc * 32 + fr) ^ swb)] = f2bf(p10[r]);
            Ps[qbr * 128 + ((wc * 32 + 16 + fr) ^ swb)] = f2bf(p11[r]);
          }
          s00 = zero; s01 = zero; s10 = zero; s11 = zero;
        }
      } else {
        const int vc = ph - 4;  // m sub-block within the 128-m tile
        const int q0 = wq * 32 + fr, q1 = wq * 32 + 16 + fr;
        short8 pa0 = *(const short8*)&Ps[q0 * 128 +
                     ((vc * 32 + kgp * 8) ^ ((q0 & 7) << 3))];
        short8 pa1 = *(const short8*)&Ps[q1 * 128 +
                     ((vc * 32 + kgp * 8) ^ ((q1 & 7) << 3))];
        __builtin_amdgcn_s_setprio(1);
        // row-sum via MFMA: D[q][*] = sum_k pa[q][k] (B = ones)
        racc0 = __builtin_amdgcn_mfma_f32_16x16x32_bf16(pa0, ones, racc0, 0, 0, 0);
        racc1 = __builtin_amdgcn_mfma_f32_16x16x32_bf16(pa1, ones, racc1, 0, 0, 0);
#pragma unroll
        for (int fb = 0; fb < 8; ++fb) {
          const int c = wc * 128 + fb * 16 + fr;
          short8 bv = *(const short8*)&Ck[buf][kgp * 4096 + c * 8];
          oa[0][fb] = __builtin_amdgcn_mfma_f32_16x16x32_bf16(pa0, bv, oa[0][fb], 0, 0, 0);
          oa[1][fb] = __builtin_amdgcn_mfma_f32_16x16x32_bf16(pa1, bv, oa[1][fb], 0, 0, 0);
        }
        __builtin_amdgcn_s_setprio(0);
      }
    }
  }
#undef LOADK
#undef LOADV
#undef WRITEK
#undef WRITEV
#undef PHASE_BAR

  // l reduction across the 4 wc-waves (each wave's racc covers ALL m -> 4x)
  __syncthreads();
  if (fr == 0) {
#pragma unroll
    for (int r = 0; r < 4; ++r) {
      lred[wq][kgp * 4 + r][wc] = racc0[r];
      lred[wq][16 + kgp * 4 + r][wc] = racc1[r];
    }
  }
  __syncthreads();
  if (t < 64) {
    float s = lred[t >> 5][t & 31][0] + lred[t >> 5][t & 31][1] +
              lred[t >> 5][t & 31][2] + lred[t >> 5][t & 31][3];
    linv[t] = 4.f / s;  // each wc wave summed all m -> sum is 4x true l
  }
  __syncthreads();
  // scale + transpose-stage O into Qs (Q dead), then coalesced store
#pragma unroll
  for (int i = 0; i < 2; ++i) {
    f32x4 li = *(const f32x4*)&linv[wq * 32 + i * 16 + kgp * 4];
#pragma unroll
    for (int fb = 0; fb < 8; ++fb) {
#pragma unroll
      for (int r = 0; r < 4; ++r) {
        const int q = wq * 32 + i * 16 + kgp * 4 + r;
        const int col = wc * 128 + fb * 16 + fr;
        Qs[q * 512 + (col ^ ((q & 7) << 3))] = f2bf(oa[i][fb][r] * li[r]);
      }
    }
  }
  __syncthreads();
  {
    const int row = t >> 3, c0 = (t & 7) * 64;
    const int sw = (row & 7) << 3;
    unsigned short* dst = og + (size_t)bz * BS + ((size_t)qt * 64 + row) * CCH + c0;
#pragma unroll
    for (int i = 0; i < 8; ++i)
      *(short8*)(dst + i * 8) = *(const short8*)&Qs[row * 512 + ((c0 + i * 8) ^ sw)];
  }
}

extern "C" void kernel_launch(void* const* d_in, const int* in_sizes, int n_in,
                              void* d_out, int out_size, void* d_ws, size_t ws_size,
                              hipStream_t stream) {
  const float* x = (const float*)d_in[0];
  const float* gnw = (const float*)d_in[1];
  const float* gnb = (const float*)d_in[2];
  const float* wq = (const float*)d_in[3];
  const float* bq = (const float*)d_in[4];
  const float* wk = (const float*)d_in[5];
  const float* bk = (const float*)d_in[6];
  const float* wv = (const float*)d_in[7];
  const float* bv = (const float*)d_in[8];
  const float* wp = (const float*)d_in[9];
  const float* bp = (const float*)d_in[10];
  float* out = (float*)d_out;

  const size_t BS = (size_t)NPIX * CCH;

  char* ws = (char*)d_ws;
  float* stats = (float*)ws;
  unsigned short* hT = (unsigned short*)(ws + 1024);
  unsigned short* Abuf = hT;  // aliases hT (dead after v-GEMM)
  unsigned short* qb = hT + BATCH * BS;
  unsigned short* kTb = qb + BATCH * BS;
  unsigned short* vb = kTb + BATCH * BS;
  unsigned short* wqb = vb + BATCH * BS;  // wqb..wpb contiguous (4x CCH*CCH)
  unsigned short* wkb = wqb + CCH * CCH;
  unsigned short* wvb = wkb + CCH * CCH;
  unsigned short* wpb = wvb + CCH * CCH;
  size_t need = (size_t)((char*)(wpb + CCH * CCH) - ws);
  if (ws_size < need) return;

  f32_to_bf16_4<<<dim3(256, 4), 256, 0, stream>>>(wq, wk, wv, wp, wqb,
                                                  CCH * CCH / 4);

  gn_stats<<<BATCH * NGRP, 256, 0, stream>>>(x, stats);
  gn_apply_t<<<dim3(NPIX / 64, CCH / 64, BATCH), 256, 0, stream>>>(x, stats, gnw,
                                                                   gnb, hT);

  // q[n,o] = sum_c hT[n,c] wq[o,c] + bq[o]
  gemm_bt<2, 1, 0, 2><<<dim3(4, 32, BATCH), 256, 0, stream>>>(
      hT, wqb, qb, bq, nullptr, NPIX, CCH, CCH, CCH, CCH, CCH, (long)BS, 0,
      (long)BS, 0, 1.f);
  // kT[m,o] = sum_c hT[m,c] wk[o,c] + bk[o]
  gemm_bt<2, 1, 0, 2><<<dim3(4, 32, BATCH), 256, 0, stream>>>(
      hT, wkb, kTb, bk, nullptr, NPIX, CCH, CCH, CCH, CCH, CCH, (long)BS, 0,
      (long)BS, 0, 1.f);
  // v[c,m] = sum_c' wv[c,c'] hT[m,c'] + bv[c]
  gemm_bt<1, 1, 0, 0><<<dim3(4, 32, BATCH), 256, 0, stream>>>(
      wvb, hT, vb, bv, nullptr, CCH, NPIX, CCH, CCH, CCH, NPIX, 0, (long)BS,
      (long)BS, 0, 1.f);

  const float sscale = 0.044194173824159216f;  // 512^-0.5
  attn_fused<<<BATCH * 64, 512, 0, stream>>>(qb, kTb, vb, Abuf, sscale);

  // out[o,n] = sum_c wp[o,c] AoutT[n,c] + bp[o] + x[b,o,n]
  gemm_bt<1, 0, 1, 0><<<dim3(4, 32, BATCH), 256, 0, stream>>>(
      wpb, Abuf, out, bp, x, CCH, NPIX, CCH, CCH, CCH, NPIX, 0, (long)BS,
      (long)BS, (long)BS, 1.f);
}